// Round 8
// baseline (2340.014 us; speedup 1.0000x reference)
//
#include <hip/hip_runtime.h>
#include <hip/hip_fp8.h>
#include <math.h>

#define BB 8
#define SS 2048
#define DD 512
#define LL 6
#define FFD 2048   // 4*D

typedef _Float16 half_t;
typedef __attribute__((ext_vector_type(8))) _Float16 half8;
typedef __attribute__((ext_vector_type(4))) float f32x4;

enum { EPI_NONE = 0, EPI_RELU = 2, EPI_RES = 3, EPI_ATTN = 4, EPI_QKV = 5, EPI_PV = 6 };

__device__ __forceinline__ unsigned char f2e4m3(float v) {
    __hip_fp8_e4m3 f(v);
    return f.__x;
}

// ---------------- async global->LDS, 16B per lane ----------------
__device__ __forceinline__ void gl_lds16(const void* g, void* l) {
    __builtin_amdgcn_global_load_lds(
        (const __attribute__((address_space(1))) unsigned int*)g,
        (__attribute__((address_space(3))) unsigned int*)l,
        16, 0, 0);
}

__device__ __forceinline__ void blockReduce2(float& a, float& b, float* sm) {
#pragma unroll
    for (int off = 32; off; off >>= 1) {
        a += __shfl_down(a, off);
        b += __shfl_down(b, off);
    }
    int lane = threadIdx.x & 63;
    int w = threadIdx.x >> 6;
    if (lane == 0) { sm[w] = a; sm[4 + w] = b; }
    __syncthreads();
    a = sm[0] + sm[1] + sm[2] + sm[3];
    b = sm[4] + sm[5] + sm[6] + sm[7];
    __syncthreads();
}

// ---------------- encoder ----------------
__global__ __launch_bounds__(256) void encode_kernel(
    const float* __restrict__ z, const float* __restrict__ c,
    const float* __restrict__ enc_w, const float* __restrict__ enc_b,
    float* __restrict__ x)
{
    int idx = blockIdx.x * 256 + threadIdx.x;
    int d  = idx & (DD - 1);
    int bs = idx >> 9;
    int s  = bs & (SS - 1);
    float v = z[bs] * enc_w[2 * d] + c[bs] * enc_w[2 * d + 1] + enc_b[d];
    float div = expf(-(float)(d & ~1) * (9.210340371976184f / 512.0f));
    float ang = (float)s * div;
    v += (d & 1) ? cosf(ang) : sinf(ang);
    x[idx] = v;
}

// ------- per-layer weight conversion, one dispatch: [wq|wk|wv] + ff1 + ff2 -------
__global__ __launch_bounds__(256) void convert_layer_kernel(
    const float* __restrict__ wq, const float* __restrict__ wk,
    const float* __restrict__ wv, const float* __restrict__ f1,
    const float* __restrict__ f2, half_t* __restrict__ wqkv,
    half_t* __restrict__ f1h, half_t* __restrict__ f2h)
{
    const int NQ = DD * DD;                      // 262144
    int i = blockIdx.x * 256 + threadIdx.x;
    if (i < 3 * NQ) {
        int which = i >> 18, j = i & (NQ - 1);
        const float* s = (which == 0) ? wq : (which == 1) ? wk : wv;
        wqkv[i] = (half_t)s[j];
    } else {
        int k = i - 3 * NQ;
        if (k < FFD * DD) f1h[k] = (half_t)f1[k];
        else              f2h[k - FFD * DD] = (half_t)f2[k - FFD * DD];
    }
}

// ---------------- attention bias tables: tbl[l][dist] ----------------
__global__ __launch_bounds__(256) void bias_table_kernel(
    const float* __restrict__ beta, float* __restrict__ tbl)
{
    int i = blockIdx.x * 256 + threadIdx.x;   // L*2048
    int l = i >> 11, d = i & (SS - 1);
    tbl[i] = beta[2 * l] * cosf(0.2617993877991494f * d)
           + beta[2 * l + 1] * cosf(0.008726646259971648f * d);
}

// ---------------- LN: dst(half) = LN(src)*w + b ----------------
__global__ __launch_bounds__(256) void ln_kernel(
    const float* __restrict__ src, const float* __restrict__ w,
    const float* __restrict__ b, half_t* __restrict__ dst)
{
    __shared__ float sm[8];
    size_t row = blockIdx.x;
    const float* p = src + row * DD;
    int t = threadIdx.x;
    float v0 = p[t], v1 = p[t + 256];
    float s = v0 + v1, sq = v0 * v0 + v1 * v1;
    blockReduce2(s, sq, sm);
    float mean = s * (1.0f / DD);
    float var  = sq * (1.0f / DD) - mean * mean;
    float rs   = rsqrtf(var + 1e-5f);
    dst[row * DD + t]       = (half_t)((v0 - mean) * rs * w[t] + b[t]);
    dst[row * DD + t + 256] = (half_t)((v1 - mean) * rs * w[t + 256] + b[t + 256]);
}

// -------- fused: x = LN(x, w1,b1); xn(half) = LN(x', w2,b2) --------
// (x already holds the residual sum: PV epilogue added att in-place)
__global__ __launch_bounds__(256) void ln_ln_kernel(
    float* __restrict__ x,
    const float* __restrict__ w1, const float* __restrict__ b1,
    const float* __restrict__ w2, const float* __restrict__ b2,
    half_t* __restrict__ xn)
{
    __shared__ float sm[8];
    size_t row = blockIdx.x;
    int t = threadIdx.x;
    float v0 = x[row * DD + t];
    float v1 = x[row * DD + t + 256];
    float s = v0 + v1, sq = v0 * v0 + v1 * v1;
    blockReduce2(s, sq, sm);
    float mean = s * (1.0f / DD);
    float var  = sq * (1.0f / DD) - mean * mean;
    float rs   = rsqrtf(var + 1e-5f);
    float y0 = (v0 - mean) * rs * w1[t] + b1[t];
    float y1 = (v1 - mean) * rs * w1[t + 256] + b1[t + 256];
    x[row * DD + t]       = y0;
    x[row * DD + t + 256] = y1;
    s = y0 + y1; sq = y0 * y0 + y1 * y1;
    blockReduce2(s, sq, sm);
    mean = s * (1.0f / DD);
    var  = sq * (1.0f / DD) - mean * mean;
    rs   = rsqrtf(var + 1e-5f);
    xn[row * DD + t]       = (half_t)((y0 - mean) * rs * w2[t] + b2[t]);
    xn[row * DD + t + 256] = (half_t)((y1 - mean) * rs * w2[t + 256] + b2[t + 256]);
}

// ---------------- MFMA NT GEMM (fp16 BK=32 or fp8-e4m3 BK=64) ----------------
// C[m,n] = sum_k A[m,k]*W[n,k]. Tile MT x 128, 256 thr = 4 waves, double-buffered
// pipelined K-loop (one barrier/iter). Staged row = 64 bytes for BOTH dtypes
// (fp16 x 32 elems, fp8 x 64 elems) -> identical staging geometry; fp8 runs
// 2 MFMA k-steps per staged tile (half the barriers of the fp16 shape).
// EPI_QKV : fp16 in -> fp8 out: Q(+bias), K(+biasK) row-major, V^T(+biasV, [b][d][s])
// EPI_ATTN: fp8 in -> fp8 out: exp(min(v*alpha + tbl[|m-n|], 6))  (lazy softmax)
// EPI_PV  : fp8 in -> fp32: denominator via ones-MFMA (P.1 row-sum in C-layout
//           regs, no shuffles), v*inv + x residual added in-place
// EPI_RELU: fp16 in -> fp16: relu(v + bias[n])
// EPI_RES : fp16 in -> fp32: v + bias[n] + C (in-place residual)
template<typename TIN, int MT, int EPI, int SWZ = 0>
__global__ __launch_bounds__(256) void gemm_mfma(
    const void* __restrict__ Ap, const void* __restrict__ Wp,
    const float* __restrict__ bias, void* __restrict__ Cp,
    int N, int K, float alpha,
    long long sA, long long sW, long long sC,
    const float* __restrict__ biasK, const float* __restrict__ biasV,
    unsigned char* __restrict__ Ck, unsigned char* __restrict__ Cv)
{
    constexpr int TM = MT / 32;                    // mfma m-tiles per wave
    constexpr int ES = (int)sizeof(TIN);           // 2 (f16) or 1 (fp8)
    constexpr int BK = (ES == 2) ? 32 : 64;        // k-elems per staged tile
    constexpr int NS = (ES == 2) ? 1 : 2;          // mfma k-steps per tile
    constexpr int ABYTES = MT * 64;                // 64 B per staged row
    constexpr int BBYTES = 128 * 64;
    __shared__ __align__(16) unsigned char As[2 * ABYTES];
    __shared__ __align__(16) unsigned char Bs[2 * BBYTES];

    int bxi, byi, bzi;
    if (SWZ == 1) {                                // 16 x 16 x 8 decode
        const int id = blockIdx.x;
        const int cc = id & 7, rr = id >> 3;
        bxi = rr & 15;
        const int ss = cc + 8 * (rr >> 4);
        byi = ss & 15; bzi = ss >> 4;
    } else { bxi = blockIdx.x; byi = blockIdx.y; bzi = blockIdx.z; }

    const int z = bzi;
    const unsigned char* A = (const unsigned char*)Ap + (size_t)z * sA * ES;
    const unsigned char* W = (const unsigned char*)Wp + (size_t)z * sW * ES;
    float*  Cf = (float*)Cp  + (size_t)z * sC;
    half_t* Ch = (half_t*)Cp + (size_t)z * sC;
    unsigned char* C8 = (unsigned char*)Cp + (size_t)z * sC;

    const int tid = threadIdx.x;
    const int wv = tid >> 6, ln = tid & 63;
    const int bm = bxi * MT, bn = byi * 128;
    const int wm = (wv & 1) * (MT / 2), wn = (wv >> 1) * 64;

    // staging: 64 B/row, 4 lanes/row, 16 rows per wave-chunk (both dtypes)
    const int srow  = wv * 16 + (ln >> 2);
    const int scolB = (ln & 3) * 16;
    const unsigned char* Ag = A + (size_t)(bm + srow) * K * ES + scolB;
    const unsigned char* Bg = W + (size_t)(bn + srow) * K * ES + scolB;

    f32x4 acc[TM][4] = {};
    f32x4 accd[TM] = {};                           // PV: row-sum accumulator
    const long ONES8 = 0x3838383838383838L;        // 8 x e4m3(1.0)

    const int lane15 = ln & 15, quad = ln >> 4;
    const int nIter = K / BK;

    // prologue: tile 0 -> buffer 0
    {
        unsigned char* la = As + wv * 1024;
        unsigned char* lb = Bs + wv * 1024;
        gl_lds16(Ag, la);
        if (MT == 128) gl_lds16(Ag + (size_t)64 * K * ES, la + 4096);
        gl_lds16(Bg, lb);
        gl_lds16(Bg + (size_t)64 * K * ES, lb + 4096);
    }
    __syncthreads();

    for (int it = 0; it < nIter; ++it) {
        const int cur = it & 1;
        if (it + 1 < nIter) {                      // prefetch tile it+1 -> other buf
            const size_t ko = (size_t)(it + 1) * 64;   // BK*ES = 64 bytes
            unsigned char* la = As + (cur ^ 1) * ABYTES + wv * 1024;
            unsigned char* lb = Bs + (cur ^ 1) * BBYTES + wv * 1024;
            gl_lds16(Ag + ko, la);
            if (MT == 128) gl_lds16(Ag + (size_t)64 * K * ES + ko, la + 4096);
            gl_lds16(Bg + ko, lb);
            gl_lds16(Bg + (size_t)64 * K * ES + ko, lb + 4096);
        }

        const unsigned char* Ab = As + cur * ABYTES;
        const unsigned char* Bb = Bs + cur * BBYTES;

        if constexpr (ES == 2) {
            half8 aF[TM], bF[4];
#pragma unroll
            for (int i = 0; i < TM; ++i)
                aF[i] = *(const half8*)(Ab + (wm + i * 16 + lane15) * 64 + quad * 16);
#pragma unroll
            for (int j = 0; j < 4; ++j)
                bF[j] = *(const half8*)(Bb + (wn + j * 16 + lane15) * 64 + quad * 16);
#pragma unroll
            for (int i = 0; i < TM; ++i)
#pragma unroll
                for (int j = 0; j < 4; ++j)
                    acc[i][j] = __builtin_amdgcn_mfma_f32_16x16x32_f16(
                        aF[i], bF[j], acc[i][j], 0, 0, 0);
        } else {
            long aF8[TM][NS], bF8[4][NS];
#pragma unroll
            for (int s = 0; s < NS; ++s) {
#pragma unroll
                for (int i = 0; i < TM; ++i)
                    aF8[i][s] = *(const long*)(Ab + (wm + i * 16 + lane15) * 64 + s * 32 + quad * 8);
#pragma unroll
                for (int j = 0; j < 4; ++j)
                    bF8[j][s] = *(const long*)(Bb + (wn + j * 16 + lane15) * 64 + s * 32 + quad * 8);
            }
#pragma unroll
            for (int s = 0; s < NS; ++s)
#pragma unroll
                for (int i = 0; i < TM; ++i) {
#pragma unroll
                    for (int j = 0; j < 4; ++j)
                        acc[i][j] = __builtin_amdgcn_mfma_f32_16x16x32_fp8_fp8(
                            aF8[i][s], bF8[j][s], acc[i][j], 0, 0, 0);
                    if (EPI == EPI_PV)             // row-sum = P . ones
                        accd[i] = __builtin_amdgcn_mfma_f32_16x16x32_fp8_fp8(
                            aF8[i][s], ONES8, accd[i], 0, 0, 0);
                }
        }

        __syncthreads();
    }

    float invd[TM][4];
    if (EPI == EPI_PV) {
#pragma unroll
        for (int i = 0; i < TM; ++i)
#pragma unroll
            for (int r = 0; r < 4; ++r)
                invd[i][r] = 1.0f / accd[i][r];    // D[m][n]=rowsum(m), all lanes
    }

    // epilogue; C/D layout: col = lane&15, row = quad*4 + r
#pragma unroll
    for (int i = 0; i < TM; ++i) {
        const int m0 = bm + wm + i * 16 + quad * 4;
#pragma unroll
        for (int j = 0; j < 4; ++j) {
            const int gn = bn + wn + j * 16 + lane15;
            if (EPI == EPI_QKV) {
                const int seg = gn >> 9, nn = gn & (DD - 1);
                if (seg == 2) {                    // V^T fp8, packed over rows (s)
                    unsigned int pk = 0;
#pragma unroll
                    for (int r = 0; r < 4; ++r)
                        pk |= (unsigned int)f2e4m3(acc[i][j][r] + biasV[nn]) << (8 * r);
                    const int b = m0 >> 11, s0 = m0 & (SS - 1);
                    *(unsigned int*)&Cv[((size_t)b * DD + nn) * SS + s0] = pk;
                } else {
                    const float bs = (seg == 0) ? bias[nn] : biasK[nn];
                    unsigned char* dst = (seg == 0) ? C8 : Ck;
#pragma unroll
                    for (int r = 0; r < 4; ++r)
                        dst[(size_t)(m0 + r) * DD + nn] = f2e4m3(acc[i][j][r] + bs);
                }
            } else {
#pragma unroll
                for (int r = 0; r < 4; ++r) {
                    const int gm = m0 + r;
                    float v = acc[i][j][r];
                    if (EPI == EPI_ATTN) {
                        int dist = gm - gn; if (dist < 0) dist = -dist;
                        v = __expf(fminf(v * alpha + bias[dist], 6.0f));
                        C8[(size_t)gm * N + gn] = f2e4m3(v);
                    } else if (EPI == EPI_PV) {
                        const size_t idx = (size_t)gm * N + gn;
                        Cf[idx] = v * invd[i][r] + Cf[idx];     // + x residual
                    } else if (EPI == EPI_RELU) {
                        Ch[(size_t)gm * N + gn] = (half_t)fmaxf(v + bias[gn], 0.0f);
                    } else {                        // EPI_RES
                        const size_t idx = (size_t)gm * N + gn;
                        Cf[idx] = v + bias[gn] + Cf[idx];
                    }
                }
            }
        }
    }
}

// ---------------- out = x @ out_w^T + out_b  (ODIM=1) ----------------
__global__ __launch_bounds__(256) void out_kernel(
    const float* __restrict__ x, const float* __restrict__ ow,
    const float* __restrict__ ob, float* __restrict__ out)
{
    int row = blockIdx.x * 4 + (threadIdx.x >> 6);
    int lane = threadIdx.x & 63;
    const float* p = x + (size_t)row * DD;
    float s = 0.f;
#pragma unroll
    for (int k = 0; k < 8; ++k) s += p[lane + 64 * k] * ow[lane + 64 * k];
#pragma unroll
    for (int off = 32; off; off >>= 1) s += __shfl_down(s, off);
    if (lane == 0) out[row] = s + ob[0];
}

// ---------------- launch ----------------
extern "C" void kernel_launch(void* const* d_in, const int* in_sizes, int n_in,
                              void* d_out, int out_size, void* d_ws, size_t ws_size,
                              hipStream_t stream)
{
    (void)in_sizes; (void)n_in; (void)out_size; (void)ws_size;
    const float* z     = (const float*)d_in[0];
    const float* c     = (const float*)d_in[1];
    const float* enc_w = (const float*)d_in[2];
    const float* enc_b = (const float*)d_in[3];
    const float* beta  = (const float*)d_in[4];
    const float* wq    = (const float*)d_in[5];
    const float* bq    = (const float*)d_in[6];
    const float* wk    = (const float*)d_in[7];
    const float* bk    = (const float*)d_in[8];
    const float* wv    = (const float*)d_in[9];
    const float* bv    = (const float*)d_in[10];
    const float* ln1w  = (const float*)d_in[11];
    const float* ln1b  = (const float*)d_in[12];
    const float* ln2w  = (const float*)d_in[13];
    const float* ln2b  = (const float*)d_in[14];
    const float* ff1w  = (const float*)d_in[15];
    const float* ff1b  = (const float*)d_in[16];
    const float* ff2w  = (const float*)d_in[17];
    const float* ff2b  = (const float*)d_in[18];
    const float* ow    = (const float*)d_in[19];
    const float* ob    = (const float*)d_in[20];

    const size_t BSD = (size_t)BB * SS * DD;   // 8.39M
    const size_t BSS = (size_t)BB * SS * SS;   // 33.6M

    // Workspace: ~182 MB total.
    char* p = (char*)d_ws;
    float*  x    = (float*)p;  p += BSD * 4;            // 33.55 MB
    half_t* xnh  = (half_t*)p; p += BSD * 2;            // 16.78 MB
    unsigned char* sch = (unsigned char*)p; p += BSS;   // 33.55 MB  fp8 exp-scores
    unsigned char* qh  = (unsigned char*)p; p += BSD;   // 8.39 MB
    unsigned char* kh  = (unsigned char*)p; p += BSD;   // 8.39 MB
    unsigned char* vth = (unsigned char*)p; p += BSD;   // 8.39 MB  [B][D][S]
    half_t* hh   = (half_t*)p; p += (size_t)BB * SS * FFD * 2;   // 67.11 MB
    half_t* wqkv = (half_t*)p; p += (size_t)3 * DD * DD * 2;     // 1.57 MB
    half_t* f1h  = (half_t*)p; p += (size_t)FFD * DD * 2;        // 2.10 MB
    half_t* f2h  = (half_t*)p; p += (size_t)FFD * DD * 2;        // 2.10 MB
    float*  tbl  = (float*)p;                                    // 48 KB

    const float alpha = 0.044194173824159216f;      // 1/sqrt(512)
    const int BS = BB * SS;
    const long long sQ = (long long)SS * DD, sP = (long long)SS * SS,
                    sV = (long long)DD * SS;
    const int CONV_BLKS = (3 * DD * DD + 2 * FFD * DD) / 256;   // 11264

    bias_table_kernel<<<LL * SS / 256, 256, 0, stream>>>(beta, tbl);
    encode_kernel<<<BS * DD / 256, 256, 0, stream>>>(z, c, enc_w, enc_b, x);

    for (int l = 0; l < LL; ++l) {
        convert_layer_kernel<<<CONV_BLKS, 256, 0, stream>>>(
            wq + (size_t)l * DD * DD, wk + (size_t)l * DD * DD,
            wv + (size_t)l * DD * DD, ff1w + (size_t)l * FFD * DD,
            ff2w + (size_t)l * DD * FFD, wqkv, f1h, f2h);

        ln_kernel<<<BS, 256, 0, stream>>>(x, ln1w + l * DD, ln1b + l * DD, xnh);

        // fused QKV (fp16 in, fp8 out): one dispatch, 1536 blocks
        gemm_mfma<half_t, 128, EPI_QKV><<<dim3(BS / 128, 12, 1), 256, 0, stream>>>(
            xnh, wqkv, bq + l * DD, qh, 1536, DD, 0, 0, 0, 0,
            bk + l * DD, bv + l * DD, kh, vth);

        // QK^T (fp8 x fp8, BK=64) -> exp(s*alpha + cos-bias) as fp8
        gemm_mfma<unsigned char, 128, EPI_ATTN, 1><<<dim3(2048, 1, 1), 256, 0, stream>>>(
            qh, kh, tbl + l * SS, sch, SS, DD, alpha, sQ, sQ, sP,
            nullptr, nullptr, nullptr, nullptr);

        // P @ V (fp8 x fp8, BK=64), ones-MFMA denominator, +x residual in-place
        gemm_mfma<unsigned char, 64, EPI_PV><<<dim3(SS / 64, DD / 128, BB), 256, 0, stream>>>(
            sch, vth, nullptr, x, DD, SS, 0, sP, sV, sQ,
            nullptr, nullptr, nullptr, nullptr);

        ln_ln_kernel<<<BS, 256, 0, stream>>>(x, ln1w + l * DD, ln1b + l * DD,
                                             ln2w + l * DD, ln2b + l * DD, xnh);

        // FFN (fp16)
        gemm_mfma<half_t, 128, EPI_RELU><<<dim3(BS / 128, FFD / 128, 1), 256, 0, stream>>>(
            xnh, f1h, ff1b + l * FFD, hh, FFD, DD, 0, 0, 0, 0,
            nullptr, nullptr, nullptr, nullptr);
        gemm_mfma<half_t, 64, EPI_RES><<<dim3(BS / 64, DD / 128, 1), 256, 0, stream>>>(
            hh, f2h, ff2b + l * DD, x, DD, FFD, 0, 0, 0, 0,
            nullptr, nullptr, nullptr, nullptr);
    }

    out_kernel<<<BS / 4, 256, 0, stream>>>(x, ow, ob, (float*)d_out);
}

// Round 9
// 1829.243 us; speedup vs baseline: 1.2792x; 1.2792x over previous
//
#include <hip/hip_runtime.h>
#include <hip/hip_fp8.h>
#include <math.h>

#define BB 8
#define SS 2048
#define DD 512
#define LL 6
#define FFD 2048   // 4*D

typedef _Float16 half_t;
typedef __attribute__((ext_vector_type(8))) _Float16 half8;
typedef __attribute__((ext_vector_type(4))) float f32x4;

enum { EPI_NONE = 0, EPI_RELU = 2, EPI_RES = 3, EPI_ATTN = 4, EPI_QKV = 5, EPI_PV = 6 };

__device__ __forceinline__ unsigned char f2e4m3(float v) {
    __hip_fp8_e4m3 f(v);
    return f.__x;
}

// ---------------- async global->LDS, 16B per lane ----------------
__device__ __forceinline__ void gl_lds16(const void* g, void* l) {
    __builtin_amdgcn_global_load_lds(
        (const __attribute__((address_space(1))) unsigned int*)g,
        (__attribute__((address_space(3))) unsigned int*)l,
        16, 0, 0);
}

__device__ __forceinline__ void blockReduce2(float& a, float& b, float* sm) {
#pragma unroll
    for (int off = 32; off; off >>= 1) {
        a += __shfl_down(a, off);
        b += __shfl_down(b, off);
    }
    int lane = threadIdx.x & 63;
    int w = threadIdx.x >> 6;
    if (lane == 0) { sm[w] = a; sm[4 + w] = b; }
    __syncthreads();
    a = sm[0] + sm[1] + sm[2] + sm[3];
    b = sm[4] + sm[5] + sm[6] + sm[7];
    __syncthreads();
}

// ---------------- encoder ----------------
__global__ __launch_bounds__(256) void encode_kernel(
    const float* __restrict__ z, const float* __restrict__ c,
    const float* __restrict__ enc_w, const float* __restrict__ enc_b,
    float* __restrict__ x)
{
    int idx = blockIdx.x * 256 + threadIdx.x;
    int d  = idx & (DD - 1);
    int bs = idx >> 9;
    int s  = bs & (SS - 1);
    float v = z[bs] * enc_w[2 * d] + c[bs] * enc_w[2 * d + 1] + enc_b[d];
    float div = expf(-(float)(d & ~1) * (9.210340371976184f / 512.0f));
    float ang = (float)s * div;
    v += (d & 1) ? cosf(ang) : sinf(ang);
    x[idx] = v;
}

// ------- per-layer weight conversion, one dispatch: [wq|wk|wv] + ff1 + ff2 -------
__global__ __launch_bounds__(256) void convert_layer_kernel(
    const float* __restrict__ wq, const float* __restrict__ wk,
    const float* __restrict__ wv, const float* __restrict__ f1,
    const float* __restrict__ f2, half_t* __restrict__ wqkv,
    half_t* __restrict__ f1h, half_t* __restrict__ f2h)
{
    const int NQ = DD * DD;                      // 262144
    int i = blockIdx.x * 256 + threadIdx.x;
    if (i < 3 * NQ) {
        int which = i >> 18, j = i & (NQ - 1);
        const float* s = (which == 0) ? wq : (which == 1) ? wk : wv;
        wqkv[i] = (half_t)s[j];
    } else {
        int k = i - 3 * NQ;
        if (k < FFD * DD) f1h[k] = (half_t)f1[k];
        else              f2h[k - FFD * DD] = (half_t)f2[k - FFD * DD];
    }
}

// ---------------- attention bias tables: tbl[l][dist] ----------------
__global__ __launch_bounds__(256) void bias_table_kernel(
    const float* __restrict__ beta, float* __restrict__ tbl)
{
    int i = blockIdx.x * 256 + threadIdx.x;   // L*2048
    int l = i >> 11, d = i & (SS - 1);
    tbl[i] = beta[2 * l] * cosf(0.2617993877991494f * d)
           + beta[2 * l + 1] * cosf(0.008726646259971648f * d);
}

// ---------------- LN: dst(half) = LN(src)*w + b ----------------
__global__ __launch_bounds__(256) void ln_kernel(
    const float* __restrict__ src, const float* __restrict__ w,
    const float* __restrict__ b, half_t* __restrict__ dst)
{
    __shared__ float sm[8];
    size_t row = blockIdx.x;
    const float* p = src + row * DD;
    int t = threadIdx.x;
    float v0 = p[t], v1 = p[t + 256];
    float s = v0 + v1, sq = v0 * v0 + v1 * v1;
    blockReduce2(s, sq, sm);
    float mean = s * (1.0f / DD);
    float var  = sq * (1.0f / DD) - mean * mean;
    float rs   = rsqrtf(var + 1e-5f);
    dst[row * DD + t]       = (half_t)((v0 - mean) * rs * w[t] + b[t]);
    dst[row * DD + t + 256] = (half_t)((v1 - mean) * rs * w[t + 256] + b[t + 256]);
}

// -------- fused: x = LN(x, w1,b1); xn(half) = LN(x', w2,b2) --------
// (x already holds the residual sum: PV epilogue added att in-place)
__global__ __launch_bounds__(256) void ln_ln_kernel(
    float* __restrict__ x,
    const float* __restrict__ w1, const float* __restrict__ b1,
    const float* __restrict__ w2, const float* __restrict__ b2,
    half_t* __restrict__ xn)
{
    __shared__ float sm[8];
    size_t row = blockIdx.x;
    int t = threadIdx.x;
    float v0 = x[row * DD + t];
    float v1 = x[row * DD + t + 256];
    float s = v0 + v1, sq = v0 * v0 + v1 * v1;
    blockReduce2(s, sq, sm);
    float mean = s * (1.0f / DD);
    float var  = sq * (1.0f / DD) - mean * mean;
    float rs   = rsqrtf(var + 1e-5f);
    float y0 = (v0 - mean) * rs * w1[t] + b1[t];
    float y1 = (v1 - mean) * rs * w1[t + 256] + b1[t + 256];
    x[row * DD + t]       = y0;
    x[row * DD + t + 256] = y1;
    s = y0 + y1; sq = y0 * y0 + y1 * y1;
    blockReduce2(s, sq, sm);
    mean = s * (1.0f / DD);
    var  = sq * (1.0f / DD) - mean * mean;
    rs   = rsqrtf(var + 1e-5f);
    xn[row * DD + t]       = (half_t)((y0 - mean) * rs * w2[t] + b2[t]);
    xn[row * DD + t + 256] = (half_t)((y1 - mean) * rs * w2[t + 256] + b2[t + 256]);
}

// ---------------- MFMA NT GEMM (fp16 BK=32 or fp8-e4m3 BK=64) ----------------
// C[m,n] = sum_k A[m,k]*W[n,k]. Tile MT x 128, 256 thr = 4 waves, double-buffered
// pipelined K-loop (one barrier/iter). Staged row = 64 B for both dtypes.
// LDS XOR swizzle (bank-conflict fix): row r's 16-B chunk c is stored at LDS
// chunk c ^ (((r&15)>>1)&3). Staging picks the permuted global chunk per lane
// (gl_lds lane->LDS mapping is fixed); reads XOR the chunk index with
// (lane15>>1)&3. Turns the 8-way b128/b64 conflicts into 2-way (free).
// EPI_QKV : fp16 in -> fp8 out: Q(+bias), K(+biasK) row-major, V^T(+biasV, [b][d][s])
// EPI_ATTN: fp8 in -> fp8 out: exp(min(v*alpha + tbl[|m-n|], 6))  (lazy softmax)
// EPI_PV  : fp8 in -> fp32: denominator via ones-MFMA, v*inv + x residual in-place
// EPI_RELU: fp16 in -> fp16: relu(v + bias[n])
// EPI_RES : fp16 in -> fp32: v + bias[n] + C (in-place residual)
template<typename TIN, int MT, int EPI, int SWZ = 0>
__global__ __launch_bounds__(256) void gemm_mfma(
    const void* __restrict__ Ap, const void* __restrict__ Wp,
    const float* __restrict__ bias, void* __restrict__ Cp,
    int N, int K, float alpha,
    long long sA, long long sW, long long sC,
    const float* __restrict__ biasK, const float* __restrict__ biasV,
    unsigned char* __restrict__ Ck, unsigned char* __restrict__ Cv)
{
    constexpr int TM = MT / 32;                    // mfma m-tiles per wave
    constexpr int ES = (int)sizeof(TIN);           // 2 (f16) or 1 (fp8)
    constexpr int BK = (ES == 2) ? 32 : 64;        // k-elems per staged tile
    constexpr int NS = (ES == 2) ? 1 : 2;          // mfma k-steps per tile
    constexpr int ABYTES = MT * 64;                // 64 B per staged row
    constexpr int BBYTES = 128 * 64;
    __shared__ __align__(16) unsigned char As[2 * ABYTES];
    __shared__ __align__(16) unsigned char Bs[2 * BBYTES];

    int bxi, byi, bzi;
    if (SWZ == 1) {                                // 16 x 16 x 8 decode
        const int id = blockIdx.x;
        const int cc = id & 7, rr = id >> 3;
        bxi = rr & 15;
        const int ss = cc + 8 * (rr >> 4);
        byi = ss & 15; bzi = ss >> 4;
    } else { bxi = blockIdx.x; byi = blockIdx.y; bzi = blockIdx.z; }

    const int z = bzi;
    const unsigned char* A = (const unsigned char*)Ap + (size_t)z * sA * ES;
    const unsigned char* W = (const unsigned char*)Wp + (size_t)z * sW * ES;
    float*  Cf = (float*)Cp  + (size_t)z * sC;
    half_t* Ch = (half_t*)Cp + (size_t)z * sC;
    unsigned char* C8 = (unsigned char*)Cp + (size_t)z * sC;

    const int tid = threadIdx.x;
    const int wv = tid >> 6, ln = tid & 63;
    const int bm = bxi * MT, bn = byi * 128;
    const int wm = (wv & 1) * (MT / 2), wn = (wv >> 1) * 64;

    // staging: 64 B/row, 4 lanes/row; lane loads the XOR-permuted global chunk
    const int srow  = wv * 16 + (ln >> 2);
    const int scolB = (((ln & 3) ^ ((ln >> 3) & 3))) * 16;
    const unsigned char* Ag = A + (size_t)(bm + srow) * K * ES + scolB;
    const unsigned char* Bg = W + (size_t)(bn + srow) * K * ES + scolB;

    f32x4 acc[TM][4] = {};
    f32x4 accd[TM] = {};                           // PV: row-sum accumulator
    const long ONES8 = 0x3838383838383838L;        // 8 x e4m3(1.0)

    const int lane15 = ln & 15, quad = ln >> 4;
    const int sw = (lane15 >> 1) & 3;              // read-side chunk XOR
    const int nIter = K / BK;

    // prologue: tile 0 -> buffer 0
    {
        unsigned char* la = As + wv * 1024;
        unsigned char* lb = Bs + wv * 1024;
        gl_lds16(Ag, la);
        if (MT == 128) gl_lds16(Ag + (size_t)64 * K * ES, la + 4096);
        gl_lds16(Bg, lb);
        gl_lds16(Bg + (size_t)64 * K * ES, lb + 4096);
    }
    __syncthreads();

    for (int it = 0; it < nIter; ++it) {
        const int cur = it & 1;
        if (it + 1 < nIter) {                      // prefetch tile it+1 -> other buf
            const size_t ko = (size_t)(it + 1) * 64;   // BK*ES = 64 bytes
            unsigned char* la = As + (cur ^ 1) * ABYTES + wv * 1024;
            unsigned char* lb = Bs + (cur ^ 1) * BBYTES + wv * 1024;
            gl_lds16(Ag + ko, la);
            if (MT == 128) gl_lds16(Ag + (size_t)64 * K * ES + ko, la + 4096);
            gl_lds16(Bg + ko, lb);
            gl_lds16(Bg + (size_t)64 * K * ES + ko, lb + 4096);
        }

        const unsigned char* Ab = As + cur * ABYTES;
        const unsigned char* Bb = Bs + cur * BBYTES;

        if constexpr (ES == 2) {
            const int cB = (quad ^ sw) * 16;       // swizzled 16-B chunk
            half8 aF[TM], bF[4];
#pragma unroll
            for (int i = 0; i < TM; ++i)
                aF[i] = *(const half8*)(Ab + (wm + i * 16 + lane15) * 64 + cB);
#pragma unroll
            for (int j = 0; j < 4; ++j)
                bF[j] = *(const half8*)(Bb + (wn + j * 16 + lane15) * 64 + cB);
#pragma unroll
            for (int i = 0; i < TM; ++i)
#pragma unroll
                for (int j = 0; j < 4; ++j)
                    acc[i][j] = __builtin_amdgcn_mfma_f32_16x16x32_f16(
                        aF[i], bF[j], acc[i][j], 0, 0, 0);
        } else {
            long aF8[TM][NS], bF8[4][NS];
#pragma unroll
            for (int s = 0; s < NS; ++s) {
                const int cB = (((s * 2 + (quad >> 1)) ^ sw) * 16) + (quad & 1) * 8;
#pragma unroll
                for (int i = 0; i < TM; ++i)
                    aF8[i][s] = *(const long*)(Ab + (wm + i * 16 + lane15) * 64 + cB);
#pragma unroll
                for (int j = 0; j < 4; ++j)
                    bF8[j][s] = *(const long*)(Bb + (wn + j * 16 + lane15) * 64 + cB);
            }
#pragma unroll
            for (int s = 0; s < NS; ++s)
#pragma unroll
                for (int i = 0; i < TM; ++i) {
#pragma unroll
                    for (int j = 0; j < 4; ++j)
                        acc[i][j] = __builtin_amdgcn_mfma_f32_16x16x32_fp8_fp8(
                            aF8[i][s], bF8[j][s], acc[i][j], 0, 0, 0);
                    if (EPI == EPI_PV)             // row-sum = P . ones
                        accd[i] = __builtin_amdgcn_mfma_f32_16x16x32_fp8_fp8(
                            aF8[i][s], ONES8, accd[i], 0, 0, 0);
                }
        }

        __syncthreads();
    }

    float invd[TM][4];
    if (EPI == EPI_PV) {
#pragma unroll
        for (int i = 0; i < TM; ++i)
#pragma unroll
            for (int r = 0; r < 4; ++r)
                invd[i][r] = 1.0f / accd[i][r];    // D[m][n]=rowsum(m), all lanes
    }

    // epilogue; C/D layout: col = lane&15, row = quad*4 + r
#pragma unroll
    for (int i = 0; i < TM; ++i) {
        const int m0 = bm + wm + i * 16 + quad * 4;
#pragma unroll
        for (int j = 0; j < 4; ++j) {
            const int gn = bn + wn + j * 16 + lane15;
            if (EPI == EPI_QKV) {
                const int seg = gn >> 9, nn = gn & (DD - 1);
                if (seg == 2) {                    // V^T fp8, packed over rows (s)
                    unsigned int pk = 0;
#pragma unroll
                    for (int r = 0; r < 4; ++r)
                        pk |= (unsigned int)f2e4m3(acc[i][j][r] + biasV[nn]) << (8 * r);
                    const int b = m0 >> 11, s0 = m0 & (SS - 1);
                    *(unsigned int*)&Cv[((size_t)b * DD + nn) * SS + s0] = pk;
                } else {
                    const float bs = (seg == 0) ? bias[nn] : biasK[nn];
                    unsigned char* dst = (seg == 0) ? C8 : Ck;
#pragma unroll
                    for (int r = 0; r < 4; ++r)
                        dst[(size_t)(m0 + r) * DD + nn] = f2e4m3(acc[i][j][r] + bs);
                }
            } else {
#pragma unroll
                for (int r = 0; r < 4; ++r) {
                    const int gm = m0 + r;
                    float v = acc[i][j][r];
                    if (EPI == EPI_ATTN) {
                        int dist = gm - gn; if (dist < 0) dist = -dist;
                        v = __expf(fminf(v * alpha + bias[dist], 6.0f));
                        C8[(size_t)gm * N + gn] = f2e4m3(v);
                    } else if (EPI == EPI_PV) {
                        const size_t idx = (size_t)gm * N + gn;
                        Cf[idx] = v * invd[i][r] + Cf[idx];     // + x residual
                    } else if (EPI == EPI_RELU) {
                        Ch[(size_t)gm * N + gn] = (half_t)fmaxf(v + bias[gn], 0.0f);
                    } else {                        // EPI_RES
                        const size_t idx = (size_t)gm * N + gn;
                        Cf[idx] = v + bias[gn] + Cf[idx];
                    }
                }
            }
        }
    }
}

// ---------------- out = x @ out_w^T + out_b  (ODIM=1) ----------------
__global__ __launch_bounds__(256) void out_kernel(
    const float* __restrict__ x, const float* __restrict__ ow,
    const float* __restrict__ ob, float* __restrict__ out)
{
    int row = blockIdx.x * 4 + (threadIdx.x >> 6);
    int lane = threadIdx.x & 63;
    const float* p = x + (size_t)row * DD;
    float s = 0.f;
#pragma unroll
    for (int k = 0; k < 8; ++k) s += p[lane + 64 * k] * ow[lane + 64 * k];
#pragma unroll
    for (int off = 32; off; off >>= 1) s += __shfl_down(s, off);
    if (lane == 0) out[row] = s + ob[0];
}

// ---------------- launch ----------------
extern "C" void kernel_launch(void* const* d_in, const int* in_sizes, int n_in,
                              void* d_out, int out_size, void* d_ws, size_t ws_size,
                              hipStream_t stream)
{
    (void)in_sizes; (void)n_in; (void)out_size; (void)ws_size;
    const float* z     = (const float*)d_in[0];
    const float* c     = (const float*)d_in[1];
    const float* enc_w = (const float*)d_in[2];
    const float* enc_b = (const float*)d_in[3];
    const float* beta  = (const float*)d_in[4];
    const float* wq    = (const float*)d_in[5];
    const float* bq    = (const float*)d_in[6];
    const float* wk    = (const float*)d_in[7];
    const float* bk    = (const float*)d_in[8];
    const float* wv    = (const float*)d_in[9];
    const float* bv    = (const float*)d_in[10];
    const float* ln1w  = (const float*)d_in[11];
    const float* ln1b  = (const float*)d_in[12];
    const float* ln2w  = (const float*)d_in[13];
    const float* ln2b  = (const float*)d_in[14];
    const float* ff1w  = (const float*)d_in[15];
    const float* ff1b  = (const float*)d_in[16];
    const float* ff2w  = (const float*)d_in[17];
    const float* ff2b  = (const float*)d_in[18];
    const float* ow    = (const float*)d_in[19];
    const float* ob    = (const float*)d_in[20];

    const size_t BSD = (size_t)BB * SS * DD;   // 8.39M
    const size_t BSS = (size_t)BB * SS * SS;   // 33.6M

    // Workspace: ~182 MB total.
    char* p = (char*)d_ws;
    float*  x    = (float*)p;  p += BSD * 4;            // 33.55 MB
    half_t* xnh  = (half_t*)p; p += BSD * 2;            // 16.78 MB
    unsigned char* sch = (unsigned char*)p; p += BSS;   // 33.55 MB  fp8 exp-scores
    unsigned char* qh  = (unsigned char*)p; p += BSD;   // 8.39 MB
    unsigned char* kh  = (unsigned char*)p; p += BSD;   // 8.39 MB
    unsigned char* vth = (unsigned char*)p; p += BSD;   // 8.39 MB  [B][D][S]
    half_t* hh   = (half_t*)p; p += (size_t)BB * SS * FFD * 2;   // 67.11 MB
    half_t* wqkv = (half_t*)p; p += (size_t)3 * DD * DD * 2;     // 1.57 MB
    half_t* f1h  = (half_t*)p; p += (size_t)FFD * DD * 2;        // 2.10 MB
    half_t* f2h  = (half_t*)p; p += (size_t)FFD * DD * 2;        // 2.10 MB
    float*  tbl  = (float*)p;                                    // 48 KB

    const float alpha = 0.044194173824159216f;      // 1/sqrt(512)
    const int BS = BB * SS;
    const long long sQ = (long long)SS * DD, sP = (long long)SS * SS,
                    sV = (long long)DD * SS;
    const int CONV_BLKS = (3 * DD * DD + 2 * FFD * DD) / 256;   // 11264

    bias_table_kernel<<<LL * SS / 256, 256, 0, stream>>>(beta, tbl);
    encode_kernel<<<BS * DD / 256, 256, 0, stream>>>(z, c, enc_w, enc_b, x);

    for (int l = 0; l < LL; ++l) {
        convert_layer_kernel<<<CONV_BLKS, 256, 0, stream>>>(
            wq + (size_t)l * DD * DD, wk + (size_t)l * DD * DD,
            wv + (size_t)l * DD * DD, ff1w + (size_t)l * FFD * DD,
            ff2w + (size_t)l * DD * FFD, wqkv, f1h, f2h);

        ln_kernel<<<BS, 256, 0, stream>>>(x, ln1w + l * DD, ln1b + l * DD, xnh);

        // fused QKV (fp16 in, fp8 out): one dispatch, 1536 blocks
        gemm_mfma<half_t, 128, EPI_QKV><<<dim3(BS / 128, 12, 1), 256, 0, stream>>>(
            xnh, wqkv, bq + l * DD, qh, 1536, DD, 0, 0, 0, 0,
            bk + l * DD, bv + l * DD, kh, vth);

        // QK^T (fp8 x fp8, BK=64) -> exp(s*alpha + cos-bias) as fp8
        gemm_mfma<unsigned char, 128, EPI_ATTN, 1><<<dim3(2048, 1, 1), 256, 0, stream>>>(
            qh, kh, tbl + l * SS, sch, SS, DD, alpha, sQ, sQ, sP,
            nullptr, nullptr, nullptr, nullptr);

        // P @ V (fp8 x fp8, BK=64), ones-MFMA denominator, +x residual in-place
        gemm_mfma<unsigned char, 64, EPI_PV><<<dim3(SS / 64, DD / 128, BB), 256, 0, stream>>>(
            sch, vth, nullptr, x, DD, SS, 0, sP, sV, sQ,
            nullptr, nullptr, nullptr, nullptr);

        ln_ln_kernel<<<BS, 256, 0, stream>>>(x, ln1w + l * DD, ln1b + l * DD,
                                             ln2w + l * DD, ln2b + l * DD, xnh);

        // FFN (fp16)
        gemm_mfma<half_t, 128, EPI_RELU><<<dim3(BS / 128, FFD / 128, 1), 256, 0, stream>>>(
            xnh, f1h, ff1b + l * FFD, hh, FFD, DD, 0, 0, 0, 0,
            nullptr, nullptr, nullptr, nullptr);
        gemm_mfma<half_t, 64, EPI_RES><<<dim3(BS / 64, DD / 128, 1), 256, 0, stream>>>(
            hh, f2h, ff2b + l * DD, x, DD, FFD, 0, 0, 0, 0,
            nullptr, nullptr, nullptr, nullptr);
    }

    out_kernel<<<BS / 4, 256, 0, stream>>>(x, ow, ob, (float*)d_out);
}